// Round 5
// baseline (354.535 us; speedup 1.0000x reference)
//
#include <hip/hip_runtime.h>
#include <hip/hip_bf16.h>

#define B_ 4
#define N_ 1370
#define C_ 1024
#define H_ 16
#define DH_ 64
#define NR_ 1369
#define M_ (B_*N_)   // 5480
#define VTS_ 1408    // padded token stride for transposed V
#define ALS 64       // attn Ks/Vs LDS row stride (swizzled, no pad)
#define PLS 72       // attn Ps LDS row stride (padded)

// q pre-scale: (1/sqrt(64)) * log2(e)  -> scores feed v_exp_f32 directly
#define QSCALE 0.1803368801111f

typedef __bf16 bf16x8 __attribute__((ext_vector_type(8)));
typedef float  f32x4  __attribute__((ext_vector_type(4)));

__device__ __forceinline__ bf16x8 ld_frag(const unsigned short* p) {
    uint4 u = *(const uint4*)p;
    return __builtin_bit_cast(bf16x8, u);
}
__device__ __forceinline__ unsigned short f2bf(float f) {
    __hip_bfloat16 h = __float2bfloat16(f);
    return __builtin_bit_cast(unsigned short, h);
}
__device__ __forceinline__ float bf2f(unsigned short u) {
    return __bfloat162float(__builtin_bit_cast(__hip_bfloat16, u));
}
__device__ __forceinline__ bf16x8 ones_frag() {
    uint4 u = make_uint4(0x3F803F80u, 0x3F803F80u, 0x3F803F80u, 0x3F803F80u);
    return __builtin_bit_cast(bf16x8, u);
}

// async global->LDS, 16B per lane; LDS dst = wave-uniform base + lane*16
__device__ __forceinline__ void load_lds16(const unsigned short* g, unsigned short* l) {
    __builtin_amdgcn_global_load_lds(
        (const __attribute__((address_space(1))) unsigned int*)g,
        (__attribute__((address_space(3))) unsigned int*)l,
        16, 0, 0);
}

// ---------------------------------------------------------------------------
// split fp32 -> bf16 hi + lo
// ---------------------------------------------------------------------------
__global__ __launch_bounds__(256)
void conv_split_k(const float* __restrict__ x, unsigned short* __restrict__ hi,
                  unsigned short* __restrict__ lo, int total4) {
    int i = blockIdx.x * 256 + threadIdx.x;
    if (i >= total4) return;
    float4 v = ((const float4*)x)[i];
    ushort4 h, l;
    h.x = f2bf(v.x); l.x = f2bf(v.x - bf2f(h.x));
    h.y = f2bf(v.y); l.y = f2bf(v.y - bf2f(h.y));
    h.z = f2bf(v.z); l.z = f2bf(v.z - bf2f(h.z));
    h.w = f2bf(v.w); l.w = f2bf(v.w - bf2f(h.w));
    ((ushort4*)hi)[i] = h;
    ((ushort4*)lo)[i] = l;
}

// ---------------------------------------------------------------------------
// convert + transpose weight: w[1024][Ncol] fp32 -> hi/lo[Ncol][1024] bf16
// ---------------------------------------------------------------------------
template<bool SPLIT>
__global__ __launch_bounds__(256)
void conv_wt_k(const float* __restrict__ w, unsigned short* __restrict__ hi,
               unsigned short* __restrict__ lo, int Ncol) {
    __shared__ unsigned short Th[64][68];
    __shared__ unsigned short Tl[64][68];
    const int tid = threadIdx.x, tx = tid & 15, ty = tid >> 4;
    const int k0 = blockIdx.y * 64, n0 = blockIdx.x * 64;
    #pragma unroll
    for (int i = 0; i < 4; ++i) {
        const int k = ty + i * 16;
        float4 v = *(const float4*)&w[(size_t)(k0 + k) * Ncol + n0 + tx * 4];
        unsigned short hx = f2bf(v.x), hy = f2bf(v.y), hz = f2bf(v.z), hw = f2bf(v.w);
        Th[k][tx*4+0] = hx; Th[k][tx*4+1] = hy; Th[k][tx*4+2] = hz; Th[k][tx*4+3] = hw;
        if (SPLIT) {
            Tl[k][tx*4+0] = f2bf(v.x - bf2f(hx));
            Tl[k][tx*4+1] = f2bf(v.y - bf2f(hy));
            Tl[k][tx*4+2] = f2bf(v.z - bf2f(hz));
            Tl[k][tx*4+3] = f2bf(v.w - bf2f(hw));
        }
    }
    __syncthreads();
    #pragma unroll
    for (int i = 0; i < 4; ++i) {
        const int n = ty + i * 16;
        ushort4 o;
        o.x = Th[tx*4+0][n]; o.y = Th[tx*4+1][n]; o.z = Th[tx*4+2][n]; o.w = Th[tx*4+3][n];
        *(ushort4*)&hi[(size_t)(n0 + n) * 1024 + k0 + tx * 4] = o;
        if (SPLIT) {
            ushort4 p;
            p.x = Tl[tx*4+0][n]; p.y = Tl[tx*4+1][n]; p.z = Tl[tx*4+2][n]; p.w = Tl[tx*4+3][n];
            *(ushort4*)&lo[(size_t)(n0 + n) * 1024 + k0 + tx * 4] = p;
        }
    }
}

// ---------------------------------------------------------------------------
// MFMA GEMM, shared-B split structure.
// SPLIT=true:  acc = Ah@Bh^T + Al@Bh^T  (phase A, B staged once for 2 A-products)
//            + Ah@Bl^T                  (phase B)
// SPLIT=false: acc = Ah@Bh^T over nchunks of 64.
// 128x128 tile, BK=64, 4 waves 2x2, global_load_lds + XOR seg swizzle.
// MODE 0: fp32 out + bias. MODE 1: QKV scatter (q*QSCALE bf16, k bf16, vT bf16).
// ---------------------------------------------------------------------------
template<int MODE, bool SPLIT>
__global__ __launch_bounds__(256)
void gemm_mfma(const unsigned short* __restrict__ Ah, const unsigned short* __restrict__ Al,
               const unsigned short* __restrict__ Bh, const unsigned short* __restrict__ Bl,
               const float* __restrict__ bias, float* __restrict__ out,
               unsigned short* __restrict__ qb, unsigned short* __restrict__ kb,
               unsigned short* __restrict__ vtb, int nchunks)
{
    __shared__ __align__(16) unsigned short Ah_s[128 * 64];
    __shared__ __align__(16) unsigned short Al_s[SPLIT ? 128 * 64 : 64];
    __shared__ __align__(16) unsigned short B_s[128 * 64];

    const int tid = threadIdx.x;
    const int wave = tid >> 6, lane = tid & 63;
    const int quad = lane >> 4, l16 = lane & 15;
    const int m0 = blockIdx.y * 128, n0 = blockIdx.x * 128;
    const int mwave = (wave & 1) * 64, nwave = (wave >> 1) * 64;

    const int srow = lane >> 3;
    const int gseg = (lane & 7) ^ srow;

    f32x4 acc[4][4] = {};

    // ---- phase A: (Ah + Al) @ Bh^T (or just Ah@Bh^T when !SPLIT) ----
    for (int kc = 0; kc < nchunks; ++kc) {
        const int kof = kc * 64;
        __syncthreads();
        #pragma unroll
        for (int i = 0; i < 4; ++i) {
            const int rbase = wave * 32 + i * 8;
            int arow = m0 + rbase + srow;
            if (arow > M_ - 1) arow = M_ - 1;
            load_lds16(Ah + (size_t)arow * 1024 + kof + gseg * 8, &Ah_s[rbase * 64]);
            if (SPLIT)
                load_lds16(Al + (size_t)arow * 1024 + kof + gseg * 8, &Al_s[rbase * 64]);
            const int brow = n0 + rbase + srow;
            load_lds16(Bh + (size_t)brow * 1024 + kof + gseg * 8, &B_s[rbase * 64]);
        }
        __syncthreads();

        #pragma unroll
        for (int kh = 0; kh < 2; ++kh) {
            const int soff = (((kh * 4 + quad) ^ (l16 & 7)) << 3);
            bf16x8 a[4], b[4];
            #pragma unroll
            for (int t = 0; t < 4; ++t) {
                a[t] = ld_frag(&Ah_s[(mwave + t * 16 + l16) * 64 + soff]);
                b[t] = ld_frag(&B_s[(nwave + t * 16 + l16) * 64 + soff]);
            }
            #pragma unroll
            for (int i = 0; i < 4; ++i)
                #pragma unroll
                for (int j = 0; j < 4; ++j)
                    acc[i][j] = __builtin_amdgcn_mfma_f32_16x16x32_bf16(a[i], b[j], acc[i][j], 0, 0, 0);
            if (SPLIT) {
                bf16x8 a2[4];
                #pragma unroll
                for (int t = 0; t < 4; ++t)
                    a2[t] = ld_frag(&Al_s[(mwave + t * 16 + l16) * 64 + soff]);
                #pragma unroll
                for (int i = 0; i < 4; ++i)
                    #pragma unroll
                    for (int j = 0; j < 4; ++j)
                        acc[i][j] = __builtin_amdgcn_mfma_f32_16x16x32_bf16(a2[i], b[j], acc[i][j], 0, 0, 0);
            }
        }
    }

    // ---- phase B: Ah @ Bl^T ----
    if (SPLIT) {
        for (int kc = 0; kc < nchunks; ++kc) {
            const int kof = kc * 64;
            __syncthreads();
            #pragma unroll
            for (int i = 0; i < 4; ++i) {
                const int rbase = wave * 32 + i * 8;
                int arow = m0 + rbase + srow;
                if (arow > M_ - 1) arow = M_ - 1;
                load_lds16(Ah + (size_t)arow * 1024 + kof + gseg * 8, &Ah_s[rbase * 64]);
                const int brow = n0 + rbase + srow;
                load_lds16(Bl + (size_t)brow * 1024 + kof + gseg * 8, &B_s[rbase * 64]);
            }
            __syncthreads();

            #pragma unroll
            for (int kh = 0; kh < 2; ++kh) {
                const int soff = (((kh * 4 + quad) ^ (l16 & 7)) << 3);
                bf16x8 a[4], b[4];
                #pragma unroll
                for (int t = 0; t < 4; ++t) {
                    a[t] = ld_frag(&Ah_s[(mwave + t * 16 + l16) * 64 + soff]);
                    b[t] = ld_frag(&B_s[(nwave + t * 16 + l16) * 64 + soff]);
                }
                #pragma unroll
                for (int i = 0; i < 4; ++i)
                    #pragma unroll
                    for (int j = 0; j < 4; ++j)
                        acc[i][j] = __builtin_amdgcn_mfma_f32_16x16x32_bf16(a[i], b[j], acc[i][j], 0, 0, 0);
            }
        }
    }

    if (MODE == 0) {
        #pragma unroll
        for (int i = 0; i < 4; ++i) {
            #pragma unroll
            for (int r = 0; r < 4; ++r) {
                const int gm = m0 + mwave + i * 16 + quad * 4 + r;
                if (gm >= M_) continue;
                #pragma unroll
                for (int j = 0; j < 4; ++j) {
                    const int gn = n0 + nwave + j * 16 + l16;
                    out[(size_t)gm * 1024 + gn] = acc[i][j][r] + bias[gn];
                }
            }
        }
    } else {
        const int part = n0 >> 10;
        #pragma unroll
        for (int i = 0; i < 4; ++i) {
            #pragma unroll
            for (int r = 0; r < 4; ++r) {
                const int gm = m0 + mwave + i * 16 + quad * 4 + r;
                if (gm >= M_) continue;
                const int b = gm / N_;
                const int tok = gm - b * N_;
                #pragma unroll
                for (int j = 0; j < 4; ++j) {
                    const int gn = n0 + nwave + j * 16 + l16;
                    const float val = acc[i][j][r] + bias[gn];
                    const int cc = gn & 1023;
                    const int h = cc >> 6, d = cc & 63;
                    const int bh = b * H_ + h;
                    if (part == 0)      qb[((size_t)bh * N_ + tok) * DH_ + d] = f2bf(val * QSCALE);
                    else if (part == 1) kb[((size_t)bh * N_ + tok) * DH_ + d] = f2bf(val);
                    else                vtb[((size_t)bh * DH_ + d) * VTS_ + tok] = f2bf(val);
                }
            }
        }
    }
}

// ---------------------------------------------------------------------------
// RoPE in-place on bf16 q,k; linear, so q's pre-scale commutes.
// ---------------------------------------------------------------------------
__global__ __launch_bounds__(256)
void rope_k(unsigned short* __restrict__ q, unsigned short* __restrict__ k,
            const float* __restrict__ sinp, const float* __restrict__ cosp)
{
    const int total = B_ * H_ * NR_ * 32;
    int idx = blockIdx.x * 256 + threadIdx.x;
    if (idx >= total) return;
    const int d = idx & 31;
    const int rest = idx >> 5;
    const int n1 = rest % NR_;
    const int bh = rest / NR_;
    const size_t base = ((size_t)bh * N_ + (n1 + 1)) * DH_;

    const float s0 = sinp[n1 * DH_ + d],  s1 = sinp[n1 * DH_ + d + 32];
    const float c0 = cosp[n1 * DH_ + d],  c1 = cosp[n1 * DH_ + d + 32];

    float x1 = bf2f(q[base + d]), x2 = bf2f(q[base + d + 32]);
    q[base + d]      = f2bf(fmaf(x1, c0, -x2 * s0));
    q[base + d + 32] = f2bf(fmaf(x2, c1,  x1 * s1));
    x1 = bf2f(k[base + d]); x2 = bf2f(k[base + d + 32]);
    k[base + d]      = f2bf(fmaf(x1, c0, -x2 * s0));
    k[base + d + 32] = f2bf(fmaf(x2, c1,  x1 * s1));
}

// ---------------------------------------------------------------------------
// MFMA flash attention v2: block = (b,h) x 128 queries, 4 waves x 32 q-rows.
// No running max (scores ~N(0,1), exp2 safe in fp32). l via ones-MFMA.
// ---------------------------------------------------------------------------
__global__ __launch_bounds__(256)
void attn_k(const unsigned short* __restrict__ q, const unsigned short* __restrict__ k,
            const unsigned short* __restrict__ vt, unsigned short* __restrict__ out)
{
    __shared__ __align__(16) unsigned short Ks[64 * ALS];
    __shared__ __align__(16) unsigned short Vs[64 * ALS];
    __shared__ __align__(16) unsigned short Ps[4 * 32 * PLS];

    const int tid  = threadIdx.x;
    const int wave = tid >> 6, lane = tid & 63;
    const int quad = lane >> 4, l16 = lane & 15;
    const int srow = lane >> 3;
    const int gseg = (lane & 7) ^ srow;
    const int bh = blockIdx.y;
    const int q0 = blockIdx.x * 128;

    const unsigned short* qp  = q  + (size_t)bh * N_ * DH_;
    const unsigned short* kp  = k  + (size_t)bh * N_ * DH_;
    const unsigned short* vtp = vt + (size_t)bh * DH_ * VTS_;

    bf16x8 qf[2][2];
    #pragma unroll
    for (int s = 0; s < 2; ++s) {
        int qrow = q0 + wave * 32 + s * 16 + l16;
        if (qrow > N_ - 1) qrow = N_ - 1;
        qf[s][0] = ld_frag(qp + (size_t)qrow * DH_ + quad * 8);
        qf[s][1] = ld_frag(qp + (size_t)qrow * DH_ + 32 + quad * 8);
    }

    const bf16x8 onesv = ones_frag();
    f32x4 O[2][4] = {};
    f32x4 L[2] = {};

    unsigned short* Pw = Ps + wave * 32 * PLS;
    const int so0 = ((quad)     ^ (l16 & 7)) << 3;
    const int so1 = ((4 + quad) ^ (l16 & 7)) << 3;

    for (int ch = 0; ch < 22; ++ch) {
        const int k0 = ch * 64;
        __syncthreads();
        #pragma unroll
        for (int i = 0; i < 2; ++i) {
            const int rbase = wave * 16 + i * 8;
            int krow = k0 + rbase + srow;
            if (krow > N_ - 1) krow = N_ - 1;
            load_lds16(kp + (size_t)krow * DH_ + gseg * 8, &Ks[rbase * ALS]);
            load_lds16(vtp + (size_t)(rbase + srow) * VTS_ + k0 + gseg * 8, &Vs[rbase * ALS]);
        }
        __syncthreads();

        bf16x8 kf[4][2];
        #pragma unroll
        for (int t = 0; t < 4; ++t) {
            kf[t][0] = ld_frag(&Ks[(t * 16 + l16) * ALS + so0]);
            kf[t][1] = ld_frag(&Ks[(t * 16 + l16) * ALS + so1]);
        }
        f32x4 S[2][4];
        #pragma unroll
        for (int s = 0; s < 2; ++s) {
            #pragma unroll
            for (int t = 0; t < 4; ++t) {
                f32x4 z = {};
                z = __builtin_amdgcn_mfma_f32_16x16x32_bf16(qf[s][0], kf[t][0], z, 0, 0, 0);
                z = __builtin_amdgcn_mfma_f32_16x16x32_bf16(qf[s][1], kf[t][1], z, 0, 0, 0);
                S[s][t] = z;
            }
        }
        if (k0 + 64 > N_) {
            #pragma unroll
            for (int t = 0; t < 4; ++t) {
                if (k0 + t * 16 + l16 >= N_) {
                    #pragma unroll
                    for (int s = 0; s < 2; ++s) {
                        S[s][t][0] = -1e30f; S[s][t][1] = -1e30f;
                        S[s][t][2] = -1e30f; S[s][t][3] = -1e30f;
                    }
                }
            }
        }

        #pragma unroll
        for (int s = 0; s < 2; ++s) {
            #pragma unroll
            for (int t = 0; t < 4; ++t) {
                #pragma unroll
                for (int r = 0; r < 4; ++r) {
                    const float p = __builtin_amdgcn_exp2f(S[s][t][r]);
                    Pw[(s * 16 + quad * 4 + r) * PLS + t * 16 + l16] = f2bf(p);
                }
            }
        }
        __builtin_amdgcn_wave_barrier();

        bf16x8 pf[2][2];
        #pragma unroll
        for (int s = 0; s < 2; ++s) {
            pf[s][0] = ld_frag(&Pw[(s * 16 + l16) * PLS + quad * 8]);
            pf[s][1] = ld_frag(&Pw[(s * 16 + l16) * PLS + 32 + quad * 8]);
        }
        bf16x8 vf[4][2];
        #pragma unroll
        for (int dt = 0; dt < 4; ++dt) {
            vf[dt][0] = ld_frag(&Vs[(dt * 16 + l16) * ALS + so0]);
            vf[dt][1] = ld_frag(&Vs[(dt * 16 + l16) * ALS + so1]);
        }
        #pragma unroll
        for (int s = 0; s < 2; ++s) {
            L[s] = __builtin_amdgcn_mfma_f32_16x16x32_bf16(pf[s][0], onesv, L[s], 0, 0, 0);
            L[s] = __builtin_amdgcn_mfma_f32_16x16x32_bf16(pf[s][1], onesv, L[s], 0, 0, 0);
            #pragma unroll
            for (int dt = 0; dt < 4; ++dt) {
                O[s][dt] = __builtin_amdgcn_mfma_f32_16x16x32_bf16(pf[s][0], vf[dt][0], O[s][dt], 0, 0, 0);
                O[s][dt] = __builtin_amdgcn_mfma_f32_16x16x32_bf16(pf[s][1], vf[dt][1], O[s][dt], 0, 0, 0);
            }
        }
    }

    const int b = bh >> 4, h = bh & 15;
    #pragma unroll
    for (int s = 0; s < 2; ++s) {
        #pragma unroll
        for (int r = 0; r < 4; ++r) {
            const int qi = q0 + wave * 32 + s * 16 + quad * 4 + r;
            if (qi < N_) {
                const float inv = 1.0f / L[s][r];
                unsigned short* op = out + ((size_t)(b * N_ + qi)) * C_ + h * DH_ + l16;
                #pragma unroll
                for (int dt = 0; dt < 4; ++dt) op[dt * 16] = f2bf(O[s][dt][r] * inv);
            }
        }
    }
}

// ---------------------------------------------------------------------------
extern "C" void kernel_launch(void* const* d_in, const int* in_sizes, int n_in,
                              void* d_out, int out_size, void* d_ws, size_t ws_size,
                              hipStream_t stream) {
    const float* x      = (const float*)d_in[0];
    const float* sinp   = (const float*)d_in[1];
    const float* cosp   = (const float*)d_in[2];
    const float* w_qkv  = (const float*)d_in[3];
    const float* b_qkv  = (const float*)d_in[4];
    const float* w_proj = (const float*)d_in[5];
    const float* b_proj = (const float*)d_in[6];
    float* out = (float*)d_out;

    unsigned short* p = (unsigned short*)d_ws;
    const size_t xsz  = (size_t)M_ * C_;
    const size_t wqsz = (size_t)3 * C_ * C_;
    const size_t wpsz = (size_t)C_ * C_;
    const size_t hsz  = (size_t)B_ * H_ * N_ * DH_;
    const size_t vtsz = (size_t)B_ * H_ * DH_ * VTS_;
    unsigned short* x_hi  = p;            p += xsz;
    unsigned short* x_lo  = p;            p += xsz;
    unsigned short* wq_hi = p;            p += wqsz;
    unsigned short* wq_lo = p;            p += wqsz;
    unsigned short* wp_t  = p;            p += wpsz;
    unsigned short* q     = p;            p += hsz;
    unsigned short* k     = p;            p += hsz;
    unsigned short* vt    = p;            p += vtsz;
    unsigned short* attnb = p;            p += xsz;

    conv_split_k<<<(int)((xsz / 4 + 255) / 256), 256, 0, stream>>>(x, x_hi, x_lo, (int)(xsz / 4));
    conv_wt_k<true ><<<dim3(3 * C_ / 64, C_ / 64), 256, 0, stream>>>(w_qkv, wq_hi, wq_lo, 3 * C_);
    conv_wt_k<false><<<dim3(C_ / 64, C_ / 64), 256, 0, stream>>>(w_proj, wp_t, nullptr, C_);

    // QKV projection: shared-B split GEMM (hi*hi + lo*hi in phase A, hi*lo in phase B)
    gemm_mfma<1, true><<<dim3(3 * C_ / 128, (M_ + 127) / 128), 256, 0, stream>>>(
        x_hi, x_lo, wq_hi, wq_lo,
        b_qkv, nullptr, q, k, vt, 16);

    const int rope_total = B_ * H_ * NR_ * 32;
    rope_k<<<(rope_total + 255) / 256, 256, 0, stream>>>(q, k, sinp, cosp);

    attn_k<<<dim3((N_ + 127) / 128, B_ * H_), 256, 0, stream>>>(q, k, vt, attnb);

    gemm_mfma<0, false><<<dim3(C_ / 128, (M_ + 127) / 128), 256, 0, stream>>>(
        attnb, nullptr, wp_t, nullptr,
        b_proj, out, nullptr, nullptr, nullptr, 16);
}

// Round 6
// 306.477 us; speedup vs baseline: 1.1568x; 1.1568x over previous
//
#include <hip/hip_runtime.h>
#include <hip/hip_bf16.h>

#define B_ 4
#define N_ 1370
#define C_ 1024
#define H_ 16
#define DH_ 64
#define NR_ 1369
#define M_ (B_*N_)   // 5480
#define VTS_ 1408    // padded token stride for transposed V
#define ALS 64       // attn Ks/Vs LDS row stride (swizzled, no pad)
#define PLS 72       // attn Ps LDS row stride (padded)

// q pre-scale: (1/sqrt(64)) * log2(e)  -> scores feed v_exp_f32 directly
#define QSCALE 0.1803368801111f

typedef __bf16 bf16x8 __attribute__((ext_vector_type(8)));
typedef float  f32x4  __attribute__((ext_vector_type(4)));

__device__ __forceinline__ bf16x8 ld_frag(const unsigned short* p) {
    uint4 u = *(const uint4*)p;
    return __builtin_bit_cast(bf16x8, u);
}
__device__ __forceinline__ unsigned short f2bf(float f) {
    __hip_bfloat16 h = __float2bfloat16(f);
    return __builtin_bit_cast(unsigned short, h);
}
__device__ __forceinline__ float bf2f(unsigned short u) {
    return __bfloat162float(__builtin_bit_cast(__hip_bfloat16, u));
}
__device__ __forceinline__ bf16x8 ones_frag() {
    uint4 u = make_uint4(0x3F803F80u, 0x3F803F80u, 0x3F803F80u, 0x3F803F80u);
    return __builtin_bit_cast(bf16x8, u);
}

// async global->LDS, 16B per lane; LDS dst = wave-uniform base + lane*16
__device__ __forceinline__ void load_lds16(const unsigned short* g, unsigned short* l) {
    __builtin_amdgcn_global_load_lds(
        (const __attribute__((address_space(1))) unsigned int*)g,
        (__attribute__((address_space(3))) unsigned int*)l,
        16, 0, 0);
}

// ---------------------------------------------------------------------------
// split fp32 -> bf16 hi + lo
// ---------------------------------------------------------------------------
__global__ __launch_bounds__(256)
void conv_split_k(const float* __restrict__ x, unsigned short* __restrict__ hi,
                  unsigned short* __restrict__ lo, int total4) {
    int i = blockIdx.x * 256 + threadIdx.x;
    if (i >= total4) return;
    float4 v = ((const float4*)x)[i];
    ushort4 h, l;
    h.x = f2bf(v.x); l.x = f2bf(v.x - bf2f(h.x));
    h.y = f2bf(v.y); l.y = f2bf(v.y - bf2f(h.y));
    h.z = f2bf(v.z); l.z = f2bf(v.z - bf2f(h.z));
    h.w = f2bf(v.w); l.w = f2bf(v.w - bf2f(h.w));
    ((ushort4*)hi)[i] = h;
    ((ushort4*)lo)[i] = l;
}

// ---------------------------------------------------------------------------
// convert + transpose weight: w[1024][Ncol] fp32 -> wt[Ncol][1024] bf16
// ---------------------------------------------------------------------------
__global__ __launch_bounds__(256)
void conv_wt_k(const float* __restrict__ w, unsigned short* __restrict__ hi, int Ncol) {
    __shared__ unsigned short Th[64][68];
    const int tid = threadIdx.x, tx = tid & 15, ty = tid >> 4;
    const int k0 = blockIdx.y * 64, n0 = blockIdx.x * 64;
    #pragma unroll
    for (int i = 0; i < 4; ++i) {
        const int k = ty + i * 16;
        float4 v = *(const float4*)&w[(size_t)(k0 + k) * Ncol + n0 + tx * 4];
        Th[k][tx*4+0] = f2bf(v.x); Th[k][tx*4+1] = f2bf(v.y);
        Th[k][tx*4+2] = f2bf(v.z); Th[k][tx*4+3] = f2bf(v.w);
    }
    __syncthreads();
    #pragma unroll
    for (int i = 0; i < 4; ++i) {
        const int n = ty + i * 16;
        ushort4 o;
        o.x = Th[tx*4+0][n]; o.y = Th[tx*4+1][n]; o.z = Th[tx*4+2][n]; o.w = Th[tx*4+3][n];
        *(ushort4*)&hi[(size_t)(n0 + n) * 1024 + k0 + tx * 4] = o;
    }
}

// ---------------------------------------------------------------------------
// MFMA GEMM (m97 structure, 32 KB LDS): C = sum over 16-chunk regions A@B^T.
// Region rc = kc>>4 selects (A0,B0) or (A1,B1). 128x128 tile, BK=64,
// 4 waves 2x2, global_load_lds + XOR seg swizzle.
// MODE 0: fp32 out + bias.
// MODE 1: QKV epilogue with FUSED RoPE (q,k rounded to bf16 exactly once):
//         q*QSCALE bf16 [B,H,N,64], k bf16, v transposed bf16 [B,H,64,VTS_].
// ---------------------------------------------------------------------------
template<int MODE>
__global__ __launch_bounds__(256)
void gemm_mfma(const unsigned short* __restrict__ A0, const unsigned short* __restrict__ A1,
               const unsigned short* __restrict__ B0, const unsigned short* __restrict__ B1,
               const float* __restrict__ bias, float* __restrict__ out,
               unsigned short* __restrict__ qb, unsigned short* __restrict__ kb,
               unsigned short* __restrict__ vtb,
               const float* __restrict__ sinp, const float* __restrict__ cosp,
               int nchunks)
{
    __shared__ __align__(16) unsigned short A_s[128 * 64];
    __shared__ __align__(16) unsigned short B_s[128 * 64];

    const int tid = threadIdx.x;
    const int wave = tid >> 6, lane = tid & 63;
    const int quad = lane >> 4, l16 = lane & 15;
    const int m0 = blockIdx.y * 128, n0 = blockIdx.x * 128;
    const int mwave = (wave & 1) * 64, nwave = (wave >> 1) * 64;

    const int srow = lane >> 3;
    const int gseg = (lane & 7) ^ srow;

    f32x4 acc[4][4] = {};

    for (int kc = 0; kc < nchunks; ++kc) {
        const int rc = kc >> 4;
        const unsigned short* Ap = rc ? A1 : A0;
        const unsigned short* Bp = rc ? B1 : B0;
        const int kof = (kc & 15) * 64;

        __syncthreads();
        #pragma unroll
        for (int i = 0; i < 4; ++i) {
            const int rbase = wave * 32 + i * 8;
            int arow = m0 + rbase + srow;
            if (arow > M_ - 1) arow = M_ - 1;
            load_lds16(Ap + (size_t)arow * 1024 + kof + gseg * 8, &A_s[rbase * 64]);
            const int brow = n0 + rbase + srow;
            load_lds16(Bp + (size_t)brow * 1024 + kof + gseg * 8, &B_s[rbase * 64]);
        }
        __syncthreads();

        #pragma unroll
        for (int kh = 0; kh < 2; ++kh) {
            const int soff = (((kh * 4 + quad) ^ (l16 & 7)) << 3);
            bf16x8 a[4], b[4];
            #pragma unroll
            for (int t = 0; t < 4; ++t) {
                a[t] = ld_frag(&A_s[(mwave + t * 16 + l16) * 64 + soff]);
                b[t] = ld_frag(&B_s[(nwave + t * 16 + l16) * 64 + soff]);
            }
            #pragma unroll
            for (int i = 0; i < 4; ++i)
                #pragma unroll
                for (int j = 0; j < 4; ++j)
                    acc[i][j] = __builtin_amdgcn_mfma_f32_16x16x32_bf16(a[i], b[j], acc[i][j], 0, 0, 0);
        }
    }

    if (MODE == 0) {
        #pragma unroll
        for (int i = 0; i < 4; ++i) {
            #pragma unroll
            for (int r = 0; r < 4; ++r) {
                const int gm = m0 + mwave + i * 16 + quad * 4 + r;
                if (gm >= M_) continue;
                #pragma unroll
                for (int j = 0; j < 4; ++j) {
                    const int gn = n0 + nwave + j * 16 + l16;
                    out[(size_t)gm * 1024 + gn] = acc[i][j][r] + bias[gn];
                }
            }
        }
    } else {
        // part: 0=q, 1=k, 2=v (uniform per block since n0 is a multiple of 128)
        const int part = n0 >> 10;
        #pragma unroll
        for (int i = 0; i < 4; ++i) {
            #pragma unroll
            for (int r = 0; r < 4; ++r) {
                const int gm = m0 + mwave + i * 16 + quad * 4 + r;
                if (gm >= M_) continue;
                const int b = gm / N_;
                const int tok = gm - b * N_;

                float val[4];
                #pragma unroll
                for (int j = 0; j < 4; ++j) {
                    const int gn = n0 + nwave + j * 16 + l16;
                    val[j] = acc[i][j][r] + bias[gn];
                }

                // fused RoPE for q,k (head dim d_j = j*16 + l16; pairs (0,2),(1,3))
                if (part < 2 && tok >= 1) {
                    const float* sp = sinp + (size_t)(tok - 1) * DH_;
                    const float* cp = cosp + (size_t)(tok - 1) * DH_;
                    const float s0 = sp[l16],      s1 = sp[16 + l16];
                    const float s2 = sp[32 + l16], s3 = sp[48 + l16];
                    const float c0 = cp[l16],      c1 = cp[16 + l16];
                    const float c2 = cp[32 + l16], c3 = cp[48 + l16];
                    const float n0v = fmaf(val[0], c0, -val[2] * s0);
                    const float n1v = fmaf(val[1], c1, -val[3] * s1);
                    const float n2v = fmaf(val[2], c2,  val[0] * s2);
                    const float n3v = fmaf(val[3], c3,  val[1] * s3);
                    val[0] = n0v; val[1] = n1v; val[2] = n2v; val[3] = n3v;
                }

                #pragma unroll
                for (int j = 0; j < 4; ++j) {
                    const int gn = n0 + nwave + j * 16 + l16;
                    const int cc = gn & 1023;
                    const int h = cc >> 6, d = cc & 63;
                    const int bh = b * H_ + h;
                    if (part == 0)      qb[((size_t)bh * N_ + tok) * DH_ + d] = f2bf(val[j] * QSCALE);
                    else if (part == 1) kb[((size_t)bh * N_ + tok) * DH_ + d] = f2bf(val[j]);
                    else                vtb[((size_t)bh * DH_ + d) * VTS_ + tok] = f2bf(val[j]);
                }
            }
        }
    }
}

// ---------------------------------------------------------------------------
// MFMA flash attention v2: block = (b,h) x 128 queries, 4 waves x 32 q-rows.
// No running max (scores ~N(0,1), exp2 safe in fp32). l via ones-MFMA.
// ---------------------------------------------------------------------------
__global__ __launch_bounds__(256)
void attn_k(const unsigned short* __restrict__ q, const unsigned short* __restrict__ k,
            const unsigned short* __restrict__ vt, unsigned short* __restrict__ out)
{
    __shared__ __align__(16) unsigned short Ks[64 * ALS];
    __shared__ __align__(16) unsigned short Vs[64 * ALS];
    __shared__ __align__(16) unsigned short Ps[4 * 32 * PLS];

    const int tid  = threadIdx.x;
    const int wave = tid >> 6, lane = tid & 63;
    const int quad = lane >> 4, l16 = lane & 15;
    const int srow = lane >> 3;
    const int gseg = (lane & 7) ^ srow;
    const int bh = blockIdx.y;
    const int q0 = blockIdx.x * 128;

    const unsigned short* qp  = q  + (size_t)bh * N_ * DH_;
    const unsigned short* kp  = k  + (size_t)bh * N_ * DH_;
    const unsigned short* vtp = vt + (size_t)bh * DH_ * VTS_;

    bf16x8 qf[2][2];
    #pragma unroll
    for (int s = 0; s < 2; ++s) {
        int qrow = q0 + wave * 32 + s * 16 + l16;
        if (qrow > N_ - 1) qrow = N_ - 1;
        qf[s][0] = ld_frag(qp + (size_t)qrow * DH_ + quad * 8);
        qf[s][1] = ld_frag(qp + (size_t)qrow * DH_ + 32 + quad * 8);
    }

    const bf16x8 onesv = ones_frag();
    f32x4 O[2][4] = {};
    f32x4 L[2] = {};

    unsigned short* Pw = Ps + wave * 32 * PLS;
    const int so0 = ((quad)     ^ (l16 & 7)) << 3;
    const int so1 = ((4 + quad) ^ (l16 & 7)) << 3;

    for (int ch = 0; ch < 22; ++ch) {
        const int k0 = ch * 64;
        __syncthreads();
        #pragma unroll
        for (int i = 0; i < 2; ++i) {
            const int rbase = wave * 16 + i * 8;
            int krow = k0 + rbase + srow;
            if (krow > N_ - 1) krow = N_ - 1;
            load_lds16(kp + (size_t)krow * DH_ + gseg * 8, &Ks[rbase * ALS]);
            load_lds16(vtp + (size_t)(rbase + srow) * VTS_ + k0 + gseg * 8, &Vs[rbase * ALS]);
        }
        __syncthreads();

        bf16x8 kf[4][2];
        #pragma unroll
        for (int t = 0; t < 4; ++t) {
            kf[t][0] = ld_frag(&Ks[(t * 16 + l16) * ALS + so0]);
            kf[t][1] = ld_frag(&Ks[(t * 16 + l16) * ALS + so1]);
        }
        f32x4 S[2][4];
        #pragma unroll
        for (int s = 0; s < 2; ++s) {
            #pragma unroll
            for (int t = 0; t < 4; ++t) {
                f32x4 z = {};
                z = __builtin_amdgcn_mfma_f32_16x16x32_bf16(qf[s][0], kf[t][0], z, 0, 0, 0);
                z = __builtin_amdgcn_mfma_f32_16x16x32_bf16(qf[s][1], kf[t][1], z, 0, 0, 0);
                S[s][t] = z;
            }
        }
        if (k0 + 64 > N_) {
            #pragma unroll
            for (int t = 0; t < 4; ++t) {
                if (k0 + t * 16 + l16 >= N_) {
                    #pragma unroll
                    for (int s = 0; s < 2; ++s) {
                        S[s][t][0] = -1e30f; S[s][t][1] = -1e30f;
                        S[s][t][2] = -1e30f; S[s][t][3] = -1e30f;
                    }
                }
            }
        }

        #pragma unroll
        for (int s = 0; s < 2; ++s) {
            #pragma unroll
            for (int t = 0; t < 4; ++t) {
                #pragma unroll
                for (int r = 0; r < 4; ++r) {
                    const float p = __builtin_amdgcn_exp2f(S[s][t][r]);
                    Pw[(s * 16 + quad * 4 + r) * PLS + t * 16 + l16] = f2bf(p);
                }
            }
        }
        __builtin_amdgcn_wave_barrier();

        bf16x8 pf[2][2];
        #pragma unroll
        for (int s = 0; s < 2; ++s) {
            pf[s][0] = ld_frag(&Pw[(s * 16 + l16) * PLS + quad * 8]);
            pf[s][1] = ld_frag(&Pw[(s * 16 + l16) * PLS + 32 + quad * 8]);
        }
        bf16x8 vf[4][2];
        #pragma unroll
        for (int dt = 0; dt < 4; ++dt) {
            vf[dt][0] = ld_frag(&Vs[(dt * 16 + l16) * ALS + so0]);
            vf[dt][1] = ld_frag(&Vs[(dt * 16 + l16) * ALS + so1]);
        }
        #pragma unroll
        for (int s = 0; s < 2; ++s) {
            L[s] = __builtin_amdgcn_mfma_f32_16x16x32_bf16(pf[s][0], onesv, L[s], 0, 0, 0);
            L[s] = __builtin_amdgcn_mfma_f32_16x16x32_bf16(pf[s][1], onesv, L[s], 0, 0, 0);
            #pragma unroll
            for (int dt = 0; dt < 4; ++dt) {
                O[s][dt] = __builtin_amdgcn_mfma_f32_16x16x32_bf16(pf[s][0], vf[dt][0], O[s][dt], 0, 0, 0);
                O[s][dt] = __builtin_amdgcn_mfma_f32_16x16x32_bf16(pf[s][1], vf[dt][1], O[s][dt], 0, 0, 0);
            }
        }
    }

    const int b = bh >> 4, h = bh & 15;
    #pragma unroll
    for (int s = 0; s < 2; ++s) {
        #pragma unroll
        for (int r = 0; r < 4; ++r) {
            const int qi = q0 + wave * 32 + s * 16 + quad * 4 + r;
            if (qi < N_) {
                const float inv = 1.0f / L[s][r];
                unsigned short* op = out + ((size_t)(b * N_ + qi)) * C_ + h * DH_ + l16;
                #pragma unroll
                for (int dt = 0; dt < 4; ++dt) op[dt * 16] = f2bf(O[s][dt][r] * inv);
            }
        }
    }
}

// ---------------------------------------------------------------------------
extern "C" void kernel_launch(void* const* d_in, const int* in_sizes, int n_in,
                              void* d_out, int out_size, void* d_ws, size_t ws_size,
                              hipStream_t stream) {
    const float* x      = (const float*)d_in[0];
    const float* sinp   = (const float*)d_in[1];
    const float* cosp   = (const float*)d_in[2];
    const float* w_qkv  = (const float*)d_in[3];
    const float* b_qkv  = (const float*)d_in[4];
    const float* w_proj = (const float*)d_in[5];
    const float* b_proj = (const float*)d_in[6];
    float* out = (float*)d_out;

    unsigned short* p = (unsigned short*)d_ws;
    const size_t xsz  = (size_t)M_ * C_;
    const size_t wqsz = (size_t)3 * C_ * C_;
    const size_t wpsz = (size_t)C_ * C_;
    const size_t hsz  = (size_t)B_ * H_ * N_ * DH_;
    const size_t vtsz = (size_t)B_ * H_ * DH_ * VTS_;
    unsigned short* x_hi  = p;            p += xsz;
    unsigned short* x_lo  = p;            p += xsz;
    unsigned short* wq_t  = p;            p += wqsz;
    unsigned short* wp_t  = p;            p += wpsz;
    unsigned short* q     = p;            p += hsz;
    unsigned short* k     = p;            p += hsz;
    unsigned short* vt    = p;            p += vtsz;
    unsigned short* attnb = p;            p += xsz;

    conv_split_k<<<(int)((xsz / 4 + 255) / 256), 256, 0, stream>>>(x, x_hi, x_lo, (int)(xsz / 4));
    conv_wt_k<<<dim3(3 * C_ / 64, C_ / 64), 256, 0, stream>>>(w_qkv, wq_t, 3 * C_);
    conv_wt_k<<<dim3(C_ / 64, C_ / 64), 256, 0, stream>>>(w_proj, wp_t, C_);

    // QKV projection: 2-product split (x_hi + x_lo) @ w_hi^T, fused RoPE epilogue
    gemm_mfma<1><<<dim3(3 * C_ / 128, (M_ + 127) / 128), 256, 0, stream>>>(
        x_hi, x_lo, wq_t, wq_t,
        b_qkv, nullptr, q, k, vt, sinp, cosp, 32);

    attn_k<<<dim3((N_ + 127) / 128, B_ * H_), 256, 0, stream>>>(q, k, vt, attnb);

    gemm_mfma<0><<<dim3(C_ / 128, (M_ + 127) / 128), 256, 0, stream>>>(
        attnb, nullptr, wp_t, nullptr,
        b_proj, out, nullptr, nullptr, nullptr, nullptr, nullptr, 16);
}

// Round 7
// 290.424 us; speedup vs baseline: 1.2207x; 1.0553x over previous
//
#include <hip/hip_runtime.h>
#include <hip/hip_bf16.h>

#define B_ 4
#define N_ 1370
#define C_ 1024
#define H_ 16
#define DH_ 64
#define NR_ 1369
#define M_ (B_*N_)   // 5480
#define VTS_ 1408    // padded token stride for transposed V
#define ALS 64       // attn Ks/Vs LDS row stride (swizzled, no pad)
#define PLS 72       // attn Ps LDS row stride (padded, keeps 16B alignment)

// q pre-scale: (1/sqrt(64)) * log2(e)  -> scores feed v_exp_f32 directly
#define QSCALE 0.1803368801111f

typedef __bf16 bf16x8 __attribute__((ext_vector_type(8)));
typedef float  f32x4  __attribute__((ext_vector_type(4)));

__device__ __forceinline__ bf16x8 ld_frag(const unsigned short* p) {
    uint4 u = *(const uint4*)p;
    return __builtin_bit_cast(bf16x8, u);
}
__device__ __forceinline__ unsigned short f2bf(float f) {
    __hip_bfloat16 h = __float2bfloat16(f);
    return __builtin_bit_cast(unsigned short, h);
}
__device__ __forceinline__ float bf2f(unsigned short u) {
    return __bfloat162float(__builtin_bit_cast(__hip_bfloat16, u));
}
__device__ __forceinline__ bf16x8 ones_frag() {
    uint4 u = make_uint4(0x3F803F80u, 0x3F803F80u, 0x3F803F80u, 0x3F803F80u);
    return __builtin_bit_cast(bf16x8, u);
}

// async global->LDS, 16B per lane; LDS dst = wave-uniform base + lane*16
__device__ __forceinline__ void load_lds16(const unsigned short* g, unsigned short* l) {
    __builtin_amdgcn_global_load_lds(
        (const __attribute__((address_space(1))) unsigned int*)g,
        (__attribute__((address_space(3))) unsigned int*)l,
        16, 0, 0);
}

// ---------------------------------------------------------------------------
// split fp32 -> bf16 hi + lo
// ---------------------------------------------------------------------------
__global__ __launch_bounds__(256)
void conv_split_k(const float* __restrict__ x, unsigned short* __restrict__ hi,
                  unsigned short* __restrict__ lo, int total4) {
    int i = blockIdx.x * 256 + threadIdx.x;
    if (i >= total4) return;
    float4 v = ((const float4*)x)[i];
    ushort4 h, l;
    h.x = f2bf(v.x); l.x = f2bf(v.x - bf2f(h.x));
    h.y = f2bf(v.y); l.y = f2bf(v.y - bf2f(h.y));
    h.z = f2bf(v.z); l.z = f2bf(v.z - bf2f(h.z));
    h.w = f2bf(v.w); l.w = f2bf(v.w - bf2f(h.w));
    ((ushort4*)hi)[i] = h;
    ((ushort4*)lo)[i] = l;
}

// ---------------------------------------------------------------------------
// convert + transpose weight: w[1024][Ncol] fp32 -> wt[Ncol][1024] bf16
// ---------------------------------------------------------------------------
__global__ __launch_bounds__(256)
void conv_wt_k(const float* __restrict__ w, unsigned short* __restrict__ hi, int Ncol) {
    __shared__ unsigned short Th[64][68];
    const int tid = threadIdx.x, tx = tid & 15, ty = tid >> 4;
    const int k0 = blockIdx.y * 64, n0 = blockIdx.x * 64;
    #pragma unroll
    for (int i = 0; i < 4; ++i) {
        const int k = ty + i * 16;
        float4 v = *(const float4*)&w[(size_t)(k0 + k) * Ncol + n0 + tx * 4];
        Th[k][tx*4+0] = f2bf(v.x); Th[k][tx*4+1] = f2bf(v.y);
        Th[k][tx*4+2] = f2bf(v.z); Th[k][tx*4+3] = f2bf(v.w);
    }
    __syncthreads();
    #pragma unroll
    for (int i = 0; i < 4; ++i) {
        const int n = ty + i * 16;
        ushort4 o;
        o.x = Th[tx*4+0][n]; o.y = Th[tx*4+1][n]; o.z = Th[tx*4+2][n]; o.w = Th[tx*4+3][n];
        *(ushort4*)&hi[(size_t)(n0 + n) * 1024 + k0 + tx * 4] = o;
    }
}

// ---------------------------------------------------------------------------
// MFMA GEMM (m97 structure): C = sum over 16-chunk regions A@B^T.
// MT = M-tile (128 or 64). N-tile fixed 128. BK=64, 4 waves 2x2,
// global_load_lds + XOR seg swizzle.
// MODE 0: fp32 out + bias.
// MODE 1: QKV epilogue with FUSED RoPE (q,k rounded to bf16 exactly once):
//         q*QSCALE bf16 [B,H,N,64], k bf16, v transposed bf16 [B,H,64,VTS_].
// ---------------------------------------------------------------------------
template<int MODE, int MT>
__global__ __launch_bounds__(256)
void gemm_mfma(const unsigned short* __restrict__ A0, const unsigned short* __restrict__ A1,
               const unsigned short* __restrict__ B0, const unsigned short* __restrict__ B1,
               const float* __restrict__ bias, float* __restrict__ out,
               unsigned short* __restrict__ qb, unsigned short* __restrict__ kb,
               unsigned short* __restrict__ vtb,
               const float* __restrict__ sinp, const float* __restrict__ cosp,
               int nchunks)
{
    constexpr int MI = MT / 32;     // m-fragments per wave (and staging iters)
    __shared__ __align__(16) unsigned short A_s[MT * 64];
    __shared__ __align__(16) unsigned short B_s[128 * 64];

    const int tid = threadIdx.x;
    const int wave = tid >> 6, lane = tid & 63;
    const int quad = lane >> 4, l16 = lane & 15;
    const int m0 = blockIdx.y * MT, n0 = blockIdx.x * 128;
    const int mwave = (wave & 1) * (MT / 2), nwave = (wave >> 1) * 64;

    const int srow = lane >> 3;
    const int gseg = (lane & 7) ^ srow;

    f32x4 acc[MI][4] = {};

    for (int kc = 0; kc < nchunks; ++kc) {
        const int rc = kc >> 4;
        const unsigned short* Ap = rc ? A1 : A0;
        const unsigned short* Bp = rc ? B1 : B0;
        const int kof = (kc & 15) * 64;

        __syncthreads();
        #pragma unroll
        for (int i = 0; i < MI; ++i) {
            const int rbase = wave * (8 * MI) + i * 8;
            int arow = m0 + rbase + srow;
            if (arow > M_ - 1) arow = M_ - 1;
            load_lds16(Ap + (size_t)arow * 1024 + kof + gseg * 8, &A_s[rbase * 64]);
        }
        #pragma unroll
        for (int i = 0; i < 4; ++i) {
            const int rbase = wave * 32 + i * 8;
            const int brow = n0 + rbase + srow;
            load_lds16(Bp + (size_t)brow * 1024 + kof + gseg * 8, &B_s[rbase * 64]);
        }
        __syncthreads();

        #pragma unroll
        for (int kh = 0; kh < 2; ++kh) {
            const int soff = (((kh * 4 + quad) ^ (l16 & 7)) << 3);
            bf16x8 a[MI], b[4];
            #pragma unroll
            for (int t = 0; t < MI; ++t)
                a[t] = ld_frag(&A_s[(mwave + t * 16 + l16) * 64 + soff]);
            #pragma unroll
            for (int t = 0; t < 4; ++t)
                b[t] = ld_frag(&B_s[(nwave + t * 16 + l16) * 64 + soff]);
            #pragma unroll
            for (int i = 0; i < MI; ++i)
                #pragma unroll
                for (int j = 0; j < 4; ++j)
                    acc[i][j] = __builtin_amdgcn_mfma_f32_16x16x32_bf16(a[i], b[j], acc[i][j], 0, 0, 0);
        }
    }

    if (MODE == 0) {
        #pragma unroll
        for (int i = 0; i < MI; ++i) {
            #pragma unroll
            for (int r = 0; r < 4; ++r) {
                const int gm = m0 + mwave + i * 16 + quad * 4 + r;
                if (gm >= M_) continue;
                #pragma unroll
                for (int j = 0; j < 4; ++j) {
                    const int gn = n0 + nwave + j * 16 + l16;
                    out[(size_t)gm * 1024 + gn] = acc[i][j][r] + bias[gn];
                }
            }
        }
    } else {
        // part: 0=q, 1=k, 2=v (uniform per block since n0 is a multiple of 128)
        const int part = n0 >> 10;
        #pragma unroll
        for (int i = 0; i < MI; ++i) {
            #pragma unroll
            for (int r = 0; r < 4; ++r) {
                const int gm = m0 + mwave + i * 16 + quad * 4 + r;
                if (gm >= M_) continue;
                const int b = gm / N_;
                const int tok = gm - b * N_;

                float val[4];
                #pragma unroll
                for (int j = 0; j < 4; ++j) {
                    const int gn = n0 + nwave + j * 16 + l16;
                    val[j] = acc[i][j][r] + bias[gn];
                }

                // fused RoPE for q,k (head dim d_j = j*16 + l16; pairs (0,2),(1,3))
                if (part < 2 && tok >= 1) {
                    const float* sp = sinp + (size_t)(tok - 1) * DH_;
                    const float* cp = cosp + (size_t)(tok - 1) * DH_;
                    const float s0 = sp[l16],      s1 = sp[16 + l16];
                    const float s2 = sp[32 + l16], s3 = sp[48 + l16];
                    const float c0 = cp[l16],      c1 = cp[16 + l16];
                    const float c2 = cp[32 + l16], c3 = cp[48 + l16];
                    const float n0v = fmaf(val[0], c0, -val[2] * s0);
                    const float n1v = fmaf(val[1], c1, -val[3] * s1);
                    const float n2v = fmaf(val[2], c2,  val[0] * s2);
                    const float n3v = fmaf(val[3], c3,  val[1] * s3);
                    val[0] = n0v; val[1] = n1v; val[2] = n2v; val[3] = n3v;
                }

                #pragma unroll
                for (int j = 0; j < 4; ++j) {
                    const int gn = n0 + nwave + j * 16 + l16;
                    const int cc = gn & 1023;
                    const int h = cc >> 6, d = cc & 63;
                    const int bh = b * H_ + h;
                    if (part == 0)      qb[((size_t)bh * N_ + tok) * DH_ + d] = f2bf(val[j] * QSCALE);
                    else if (part == 1) kb[((size_t)bh * N_ + tok) * DH_ + d] = f2bf(val[j]);
                    else                vtb[((size_t)bh * DH_ + d) * VTS_ + tok] = f2bf(val[j]);
                }
            }
        }
    }
}

// ---------------------------------------------------------------------------
// MFMA flash attention v3: block = (b,h) x 128 queries, 4 waves x 32 q-rows.
// Double-buffered K/V with prefetch-after-barrier -> ONE barrier per chunk,
// global load latency hidden behind compute. No running max. l via ones-MFMA.
// ---------------------------------------------------------------------------
__global__ __launch_bounds__(256)
void attn_k(const unsigned short* __restrict__ q, const unsigned short* __restrict__ k,
            const unsigned short* __restrict__ vt, unsigned short* __restrict__ out)
{
    __shared__ __align__(16) unsigned short Ks[2][64 * ALS];
    __shared__ __align__(16) unsigned short Vs[2][64 * ALS];
    __shared__ __align__(16) unsigned short Ps[4 * 32 * PLS];

    const int tid  = threadIdx.x;
    const int wave = tid >> 6, lane = tid & 63;
    const int quad = lane >> 4, l16 = lane & 15;
    const int srow = lane >> 3;
    const int gseg = (lane & 7) ^ srow;
    const int bh = blockIdx.y;
    const int q0 = blockIdx.x * 128;

    const unsigned short* qp  = q  + (size_t)bh * N_ * DH_;
    const unsigned short* kp  = k  + (size_t)bh * N_ * DH_;
    const unsigned short* vtp = vt + (size_t)bh * DH_ * VTS_;

    bf16x8 qf[2][2];
    #pragma unroll
    for (int s = 0; s < 2; ++s) {
        int qrow = q0 + wave * 32 + s * 16 + l16;
        if (qrow > N_ - 1) qrow = N_ - 1;
        qf[s][0] = ld_frag(qp + (size_t)qrow * DH_ + quad * 8);
        qf[s][1] = ld_frag(qp + (size_t)qrow * DH_ + 32 + quad * 8);
    }

    const bf16x8 onesv = ones_frag();
    f32x4 O[2][4] = {};
    f32x4 L[2] = {};

    unsigned short* Pw = Ps + wave * 32 * PLS;
    const int so0 = ((quad)     ^ (l16 & 7)) << 3;
    const int so1 = ((4 + quad) ^ (l16 & 7)) << 3;

    // stage chunk ch into buffer buf (per-wave slice: 16 K-rows + 16 Vt-rows)
    auto stage = [&](int ch, int buf) {
        const int k0 = ch * 64;
        #pragma unroll
        for (int i = 0; i < 2; ++i) {
            const int rbase = wave * 16 + i * 8;
            int krow = k0 + rbase + srow;
            if (krow > N_ - 1) krow = N_ - 1;
            load_lds16(kp + (size_t)krow * DH_ + gseg * 8, &Ks[buf][rbase * ALS]);
            load_lds16(vtp + (size_t)(rbase + srow) * VTS_ + k0 + gseg * 8, &Vs[buf][rbase * ALS]);
        }
    };

    stage(0, 0);

    for (int ch = 0; ch < 22; ++ch) {
        const int k0 = ch * 64;
        const int cur = ch & 1;
        // barrier drains this wave's outstanding loads (vmcnt) and syncs all
        // waves: buffer `cur` is fully staged, buffer `1-cur`'s readers done.
        __syncthreads();
        if (ch + 1 < 22) stage(ch + 1, 1 - cur);

        bf16x8 kf[4][2];
        #pragma unroll
        for (int t = 0; t < 4; ++t) {
            kf[t][0] = ld_frag(&Ks[cur][(t * 16 + l16) * ALS + so0]);
            kf[t][1] = ld_frag(&Ks[cur][(t * 16 + l16) * ALS + so1]);
        }
        f32x4 S[2][4];
        #pragma unroll
        for (int s = 0; s < 2; ++s) {
            #pragma unroll
            for (int t = 0; t < 4; ++t) {
                f32x4 z = {};
                z = __builtin_amdgcn_mfma_f32_16x16x32_bf16(qf[s][0], kf[t][0], z, 0, 0, 0);
                z = __builtin_amdgcn_mfma_f32_16x16x32_bf16(qf[s][1], kf[t][1], z, 0, 0, 0);
                S[s][t] = z;
            }
        }
        if (k0 + 64 > N_) {
            #pragma unroll
            for (int t = 0; t < 4; ++t) {
                if (k0 + t * 16 + l16 >= N_) {
                    #pragma unroll
                    for (int s = 0; s < 2; ++s) {
                        S[s][t][0] = -1e30f; S[s][t][1] = -1e30f;
                        S[s][t][2] = -1e30f; S[s][t][3] = -1e30f;
                    }
                }
            }
        }

        #pragma unroll
        for (int s = 0; s < 2; ++s) {
            #pragma unroll
            for (int t = 0; t < 4; ++t) {
                #pragma unroll
                for (int r = 0; r < 4; ++r) {
                    const float p = __builtin_amdgcn_exp2f(S[s][t][r]);
                    Pw[(s * 16 + quad * 4 + r) * PLS + t * 16 + l16] = f2bf(p);
                }
            }
        }
        __builtin_amdgcn_wave_barrier();   // DS write->read order (intra-wave)

        bf16x8 pf[2][2];
        #pragma unroll
        for (int s = 0; s < 2; ++s) {
            pf[s][0] = ld_frag(&Pw[(s * 16 + l16) * PLS + quad * 8]);
            pf[s][1] = ld_frag(&Pw[(s * 16 + l16) * PLS + 32 + quad * 8]);
        }
        bf16x8 vf[4][2];
        #pragma unroll
        for (int dt = 0; dt < 4; ++dt) {
            vf[dt][0] = ld_frag(&Vs[cur][(dt * 16 + l16) * ALS + so0]);
            vf[dt][1] = ld_frag(&Vs[cur][(dt * 16 + l16) * ALS + so1]);
        }
        #pragma unroll
        for (int s = 0; s < 2; ++s) {
            L[s] = __builtin_amdgcn_mfma_f32_16x16x32_bf16(pf[s][0], onesv, L[s], 0, 0, 0);
            L[s] = __builtin_amdgcn_mfma_f32_16x16x32_bf16(pf[s][1], onesv, L[s], 0, 0, 0);
            #pragma unroll
            for (int dt = 0; dt < 4; ++dt) {
                O[s][dt] = __builtin_amdgcn_mfma_f32_16x16x32_bf16(pf[s][0], vf[dt][0], O[s][dt], 0, 0, 0);
                O[s][dt] = __builtin_amdgcn_mfma_f32_16x16x32_bf16(pf[s][1], vf[dt][1], O[s][dt], 0, 0, 0);
            }
        }
    }

    const int b = bh >> 4, h = bh & 15;
    #pragma unroll
    for (int s = 0; s < 2; ++s) {
        #pragma unroll
        for (int r = 0; r < 4; ++r) {
            const int qi = q0 + wave * 32 + s * 16 + quad * 4 + r;
            if (qi < N_) {
                const float inv = 1.0f / L[s][r];
                unsigned short* op = out + ((size_t)(b * N_ + qi)) * C_ + h * DH_ + l16;
                #pragma unroll
                for (int dt = 0; dt < 4; ++dt) op[dt * 16] = f2bf(O[s][dt][r] * inv);
            }
        }
    }
}

// ---------------------------------------------------------------------------
extern "C" void kernel_launch(void* const* d_in, const int* in_sizes, int n_in,
                              void* d_out, int out_size, void* d_ws, size_t ws_size,
                              hipStream_t stream) {
    const float* x      = (const float*)d_in[0];
    const float* sinp   = (const float*)d_in[1];
    const float* cosp   = (const float*)d_in[2];
    const float* w_qkv  = (const float*)d_in[3];
    const float* b_qkv  = (const float*)d_in[4];
    const float* w_proj = (const float*)d_in[5];
    const float* b_proj = (const float*)d_in[6];
    float* out = (float*)d_out;

    unsigned short* p = (unsigned short*)d_ws;
    const size_t xsz  = (size_t)M_ * C_;
    const size_t wqsz = (size_t)3 * C_ * C_;
    const size_t wpsz = (size_t)C_ * C_;
    const size_t hsz  = (size_t)B_ * H_ * N_ * DH_;
    const size_t vtsz = (size_t)B_ * H_ * DH_ * VTS_;
    unsigned short* x_hi  = p;            p += xsz;
    unsigned short* x_lo  = p;            p += xsz;
    unsigned short* wq_t  = p;            p += wqsz;
    unsigned short* wp_t  = p;            p += wpsz;
    unsigned short* q     = p;            p += hsz;
    unsigned short* k     = p;            p += hsz;
    unsigned short* vt    = p;            p += vtsz;
    unsigned short* attnb = p;            p += xsz;

    conv_split_k<<<(int)((xsz / 4 + 255) / 256), 256, 0, stream>>>(x, x_hi, x_lo, (int)(xsz / 4));
    conv_wt_k<<<dim3(3 * C_ / 64, C_ / 64), 256, 0, stream>>>(w_qkv, wq_t, 3 * C_);
    conv_wt_k<<<dim3(C_ / 64, C_ / 64), 256, 0, stream>>>(w_proj, wp_t, C_);

    // QKV projection: 2-product split (x_hi + x_lo) @ w_hi^T, fused RoPE epilogue
    gemm_mfma<1, 128><<<dim3(3 * C_ / 128, (M_ + 127) / 128), 256, 0, stream>>>(
        x_hi, x_lo, wq_t, wq_t,
        b_qkv, nullptr, q, k, vt, sinp, cosp, 32);

    attn_k<<<dim3((N_ + 127) / 128, B_ * H_), 256, 0, stream>>>(q, k, vt, attnb);

    // output projection: MT=64 tile -> 688 blocks (2.7/CU) vs 344 grid-starved
    gemm_mfma<0, 64><<<dim3(C_ / 128, (M_ + 63) / 64), 256, 0, stream>>>(
        attnb, nullptr, wp_t, nullptr,
        b_proj, out, nullptr, nullptr, nullptr, nullptr, nullptr, 16);
}

// Round 9
// 259.904 us; speedup vs baseline: 1.3641x; 1.1174x over previous
//
#include <hip/hip_runtime.h>
#include <hip/hip_bf16.h>

#define B_ 4
#define N_ 1370
#define C_ 1024
#define H_ 16
#define DH_ 64
#define NR_ 1369
#define M_ (B_*N_)   // 5480
#define VTS_ 1408    // padded token stride for transposed V
#define ALS 64       // attn Ks/Vs LDS row stride (swizzled, no pad)
#define PLS 72       // attn Ps LDS row stride (padded, keeps 16B alignment)

// q pre-scale: (1/sqrt(64)) * log2(e)  -> scores feed v_exp_f32 directly
#define QSCALE 0.1803368801111f

typedef _Float16 f16x8  __attribute__((ext_vector_type(8)));
typedef __bf16   bf16x8 __attribute__((ext_vector_type(8)));
typedef float    f32x4  __attribute__((ext_vector_type(4)));

__device__ __forceinline__ f16x8 ld_frag_h(const unsigned short* p) {
    uint4 u = *(const uint4*)p;
    return __builtin_bit_cast(f16x8, u);
}
__device__ __forceinline__ bf16x8 ld_frag_b(const unsigned short* p) {
    uint4 u = *(const uint4*)p;
    return __builtin_bit_cast(bf16x8, u);
}
__device__ __forceinline__ unsigned short f2h(float f) {
    _Float16 h = (_Float16)f;   // RNE
    return __builtin_bit_cast(unsigned short, h);
}
__device__ __forceinline__ unsigned short f2bf(float f) {
    __hip_bfloat16 h = __float2bfloat16(f);
    return __builtin_bit_cast(unsigned short, h);
}
__device__ __forceinline__ bf16x8 ones_bf() {
    uint4 u = make_uint4(0x3F803F80u, 0x3F803F80u, 0x3F803F80u, 0x3F803F80u);
    return __builtin_bit_cast(bf16x8, u);
}

// async global->LDS, 16B per lane; LDS dst = wave-uniform base + lane*16
__device__ __forceinline__ void load_lds16(const unsigned short* g, unsigned short* l) {
    __builtin_amdgcn_global_load_lds(
        (const __attribute__((address_space(1))) unsigned int*)g,
        (__attribute__((address_space(3))) unsigned int*)l,
        16, 0, 0);
}

// ---------------------------------------------------------------------------
// fp32 -> fp16 convert (vectorized)
// ---------------------------------------------------------------------------
__global__ __launch_bounds__(256)
void conv_x_k(const float* __restrict__ x, unsigned short* __restrict__ xo, int total4) {
    int i = blockIdx.x * 256 + threadIdx.x;
    if (i >= total4) return;
    float4 v = ((const float4*)x)[i];
    ushort4 h;
    h.x = f2h(v.x); h.y = f2h(v.y); h.z = f2h(v.z); h.w = f2h(v.w);
    ((ushort4*)xo)[i] = h;
}

// ---------------------------------------------------------------------------
// convert + transpose weight: w[1024][Ncol] fp32 -> wt[Ncol][1024] fp16
// ---------------------------------------------------------------------------
__global__ __launch_bounds__(256)
void conv_wt_k(const float* __restrict__ w, unsigned short* __restrict__ wt, int Ncol) {
    __shared__ unsigned short Th[64][68];
    const int tid = threadIdx.x, tx = tid & 15, ty = tid >> 4;
    const int k0 = blockIdx.y * 64, n0 = blockIdx.x * 64;
    #pragma unroll
    for (int i = 0; i < 4; ++i) {
        const int k = ty + i * 16;
        float4 v = *(const float4*)&w[(size_t)(k0 + k) * Ncol + n0 + tx * 4];
        Th[k][tx*4+0] = f2h(v.x); Th[k][tx*4+1] = f2h(v.y);
        Th[k][tx*4+2] = f2h(v.z); Th[k][tx*4+3] = f2h(v.w);
    }
    __syncthreads();
    #pragma unroll
    for (int i = 0; i < 4; ++i) {
        const int n = ty + i * 16;
        ushort4 o;
        o.x = Th[tx*4+0][n]; o.y = Th[tx*4+1][n]; o.z = Th[tx*4+2][n]; o.w = Th[tx*4+3][n];
        *(ushort4*)&wt[(size_t)(n0 + n) * 1024 + k0 + tx * 4] = o;
    }
}

// ---------------------------------------------------------------------------
// MFMA fp16 GEMM (m97 structure): C[M,N] = A[M,1024k] @ Bt[N,1024k]^T.
// MT = M-tile (128 or 64). N-tile fixed 128. BK=64, 4 waves 2x2,
// global_load_lds + XOR seg swizzle.
// MODE 0: fp32 out + bias.
// MODE 1: QKV epilogue with FUSED RoPE (q,k rounded once):
//         q*QSCALE fp16 [B,H,N,64], k fp16, v transposed BF16 [B,H,64,VTS_]
//         (V must be bf16: it joins the bf16 PV MFMA whose P needs bf16 range).
// ---------------------------------------------------------------------------
template<int MODE, int MT>
__global__ __launch_bounds__(256)
void gemm_mfma(const unsigned short* __restrict__ A, const unsigned short* __restrict__ Bt,
               const float* __restrict__ bias, float* __restrict__ out,
               unsigned short* __restrict__ qb, unsigned short* __restrict__ kb,
               unsigned short* __restrict__ vtb,
               const float* __restrict__ sinp, const float* __restrict__ cosp,
               int nchunks)
{
    constexpr int MI = MT / 32;     // m-fragments per wave (and staging iters)
    __shared__ __align__(16) unsigned short A_s[MT * 64];
    __shared__ __align__(16) unsigned short B_s[128 * 64];

    const int tid = threadIdx.x;
    const int wave = tid >> 6, lane = tid & 63;
    const int quad = lane >> 4, l16 = lane & 15;
    const int m0 = blockIdx.y * MT, n0 = blockIdx.x * 128;
    const int mwave = (wave & 1) * (MT / 2), nwave = (wave >> 1) * 64;

    const int srow = lane >> 3;
    const int gseg = (lane & 7) ^ srow;

    f32x4 acc[MI][4] = {};

    for (int kc = 0; kc < nchunks; ++kc) {
        const int kof = kc * 64;

        __syncthreads();
        #pragma unroll
        for (int i = 0; i < MI; ++i) {
            const int rbase = wave * (8 * MI) + i * 8;
            int arow = m0 + rbase + srow;
            if (arow > M_ - 1) arow = M_ - 1;
            load_lds16(A + (size_t)arow * 1024 + kof + gseg * 8, &A_s[rbase * 64]);
        }
        #pragma unroll
        for (int i = 0; i < 4; ++i) {
            const int rbase = wave * 32 + i * 8;
            const int brow = n0 + rbase + srow;
            load_lds16(Bt + (size_t)brow * 1024 + kof + gseg * 8, &B_s[rbase * 64]);
        }
        __syncthreads();

        #pragma unroll
        for (int kh = 0; kh < 2; ++kh) {
            const int soff = (((kh * 4 + quad) ^ (l16 & 7)) << 3);
            f16x8 a[MI], b[4];
            #pragma unroll
            for (int t = 0; t < MI; ++t)
                a[t] = ld_frag_h(&A_s[(mwave + t * 16 + l16) * 64 + soff]);
            #pragma unroll
            for (int t = 0; t < 4; ++t)
                b[t] = ld_frag_h(&B_s[(nwave + t * 16 + l16) * 64 + soff]);
            #pragma unroll
            for (int i = 0; i < MI; ++i)
                #pragma unroll
                for (int j = 0; j < 4; ++j)
                    acc[i][j] = __builtin_amdgcn_mfma_f32_16x16x32_f16(a[i], b[j], acc[i][j], 0, 0, 0);
        }
    }

    if (MODE == 0) {
        #pragma unroll
        for (int i = 0; i < MI; ++i) {
            #pragma unroll
            for (int r = 0; r < 4; ++r) {
                const int gm = m0 + mwave + i * 16 + quad * 4 + r;
                if (gm >= M_) continue;
                #pragma unroll
                for (int j = 0; j < 4; ++j) {
                    const int gn = n0 + nwave + j * 16 + l16;
                    out[(size_t)gm * 1024 + gn] = acc[i][j][r] + bias[gn];
                }
            }
        }
    } else {
        // part: 0=q, 1=k, 2=v (uniform per block since n0 is a multiple of 128)
        const int part = n0 >> 10;
        #pragma unroll
        for (int i = 0; i < MI; ++i) {
            #pragma unroll
            for (int r = 0; r < 4; ++r) {
                const int gm = m0 + mwave + i * 16 + quad * 4 + r;
                if (gm >= M_) continue;
                const int b = gm / N_;
                const int tok = gm - b * N_;

                float val[4];
                #pragma unroll
                for (int j = 0; j < 4; ++j) {
                    const int gn = n0 + nwave + j * 16 + l16;
                    val[j] = acc[i][j][r] + bias[gn];
                }

                // fused RoPE for q,k (head dim d_j = j*16 + l16; pairs (0,2),(1,3))
                if (part < 2 && tok >= 1) {
                    const float* sp = sinp + (size_t)(tok - 1) * DH_;
                    const float* cp = cosp + (size_t)(tok - 1) * DH_;
                    const float s0 = sp[l16],      s1 = sp[16 + l16];
                    const float s2 = sp[32 + l16], s3 = sp[48 + l16];
                    const float c0 = cp[l16],      c1 = cp[16 + l16];
                    const float c2 = cp[32 + l16], c3 = cp[48 + l16];
                    const float n0v = fmaf(val[0], c0, -val[2] * s0);
                    const float n1v = fmaf(val[1], c1, -val[3] * s1);
                    const float n2v = fmaf(val[2], c2,  val[0] * s2);
                    const float n3v = fmaf(val[3], c3,  val[1] * s3);
                    val[0] = n0v; val[1] = n1v; val[2] = n2v; val[3] = n3v;
                }

                #pragma unroll
                for (int j = 0; j < 4; ++j) {
                    const int gn = n0 + nwave + j * 16 + l16;
                    const int cc = gn & 1023;
                    const int h = cc >> 6, d = cc & 63;
                    const int bh = b * H_ + h;
                    if (part == 0)      qb[((size_t)bh * N_ + tok) * DH_ + d] = f2h(val[j] * QSCALE);
                    else if (part == 1) kb[((size_t)bh * N_ + tok) * DH_ + d] = f2h(val[j]);
                    else                vtb[((size_t)bh * DH_ + d) * VTS_ + tok] = f2bf(val[j]);
                }
            }
        }
    }
}

// ---------------------------------------------------------------------------
// MFMA flash attention (mixed): QK^T in fp16 (q,k values bounded), P and V in
// bf16 (P = 2^s can reach ~2^25 with this input distribution -> fp16 would
// overflow to inf -> NaN; bf16 has the range and normalization cancels it).
// Block = (b,h) x 128 queries, 4 waves x 32 q-rows. Double-buffered K/V,
// one barrier per chunk. No running max. l via bf16 ones-MFMA.
// ---------------------------------------------------------------------------
__global__ __launch_bounds__(256)
void attn_k(const unsigned short* __restrict__ q, const unsigned short* __restrict__ k,
            const unsigned short* __restrict__ vt, unsigned short* __restrict__ out)
{
    __shared__ __align__(16) unsigned short Ks[2][64 * ALS];
    __shared__ __align__(16) unsigned short Vs[2][64 * ALS];
    __shared__ __align__(16) unsigned short Ps[4 * 32 * PLS];

    const int tid  = threadIdx.x;
    const int wave = tid >> 6, lane = tid & 63;
    const int quad = lane >> 4, l16 = lane & 15;
    const int srow = lane >> 3;
    const int gseg = (lane & 7) ^ srow;
    const int bh = blockIdx.y;
    const int q0 = blockIdx.x * 128;

    const unsigned short* qp  = q  + (size_t)bh * N_ * DH_;
    const unsigned short* kp  = k  + (size_t)bh * N_ * DH_;
    const unsigned short* vtp = vt + (size_t)bh * DH_ * VTS_;

    f16x8 qf[2][2];
    #pragma unroll
    for (int s = 0; s < 2; ++s) {
        int qrow = q0 + wave * 32 + s * 16 + l16;
        if (qrow > N_ - 1) qrow = N_ - 1;
        qf[s][0] = ld_frag_h(qp + (size_t)qrow * DH_ + quad * 8);
        qf[s][1] = ld_frag_h(qp + (size_t)qrow * DH_ + 32 + quad * 8);
    }

    const bf16x8 onesv = ones_bf();
    f32x4 O[2][4] = {};
    f32x4 L[2] = {};

    unsigned short* Pw = Ps + wave * 32 * PLS;
    const int so0 = ((quad)     ^ (l16 & 7)) << 3;
    const int so1 = ((4 + quad) ^ (l16 & 7)) << 3;

    // stage chunk ch into buffer buf (per-wave slice: 16 K-rows + 16 Vt-rows)
    auto stage = [&](int ch, int buf) {
        const int k0 = ch * 64;
        #pragma unroll
        for (int i = 0; i < 2; ++i) {
            const int rbase = wave * 16 + i * 8;
            int krow = k0 + rbase + srow;
            if (krow > N_ - 1) krow = N_ - 1;
            load_lds16(kp + (size_t)krow * DH_ + gseg * 8, &Ks[buf][rbase * ALS]);
            load_lds16(vtp + (size_t)(rbase + srow) * VTS_ + k0 + gseg * 8, &Vs[buf][rbase * ALS]);
        }
    };

    stage(0, 0);

    for (int ch = 0; ch < 22; ++ch) {
        const int k0 = ch * 64;
        const int cur = ch & 1;
        __syncthreads();
        if (ch + 1 < 22) stage(ch + 1, 1 - cur);

        f16x8 kf[4][2];
        #pragma unroll
        for (int t = 0; t < 4; ++t) {
            kf[t][0] = ld_frag_h(&Ks[cur][(t * 16 + l16) * ALS + so0]);
            kf[t][1] = ld_frag_h(&Ks[cur][(t * 16 + l16) * ALS + so1]);
        }
        f32x4 S[2][4];
        #pragma unroll
        for (int s = 0; s < 2; ++s) {
            #pragma unroll
            for (int t = 0; t < 4; ++t) {
                f32x4 z = {};
                z = __builtin_amdgcn_mfma_f32_16x16x32_f16(qf[s][0], kf[t][0], z, 0, 0, 0);
                z = __builtin_amdgcn_mfma_f32_16x16x32_f16(qf[s][1], kf[t][1], z, 0, 0, 0);
                S[s][t] = z;
            }
        }
        if (k0 + 64 > N_) {
            #pragma unroll
            for (int t = 0; t < 4; ++t) {
                if (k0 + t * 16 + l16 >= N_) {
                    #pragma unroll
                    for (int s = 0; s < 2; ++s) {
                        S[s][t][0] = -1e30f; S[s][t][1] = -1e30f;
                        S[s][t][2] = -1e30f; S[s][t][3] = -1e30f;
                    }
                }
            }
        }

        #pragma unroll
        for (int s = 0; s < 2; ++s) {
            #pragma unroll
            for (int t = 0; t < 4; ++t) {
                #pragma unroll
                for (int r = 0; r < 4; ++r) {
                    const float p = __builtin_amdgcn_exp2f(S[s][t][r]);
                    Pw[(s * 16 + quad * 4 + r) * PLS + t * 16 + l16] = f2bf(p);
                }
            }
        }
        __builtin_amdgcn_wave_barrier();   // DS write->read order (intra-wave)

        bf16x8 pf[2][2];
        #pragma unroll
        for (int s = 0; s < 2; ++s) {
            pf[s][0] = ld_frag_b(&Pw[(s * 16 + l16) * PLS + quad * 8]);
            pf[s][1] = ld_frag_b(&Pw[(s * 16 + l16) * PLS + 32 + quad * 8]);
        }
        bf16x8 vf[4][2];
        #pragma unroll
        for (int dt = 0; dt < 4; ++dt) {
            vf[dt][0] = ld_frag_b(&Vs[cur][(dt * 16 + l16) * ALS + so0]);
            vf[dt][1] = ld_frag_b(&Vs[cur][(dt * 16 + l16) * ALS + so1]);
        }
        #pragma unroll
        for (int s = 0; s < 2; ++s) {
            L[s] = __builtin_amdgcn_mfma_f32_16x16x32_bf16(pf[s][0], onesv, L[s], 0, 0, 0);
            L[s] = __builtin_amdgcn_mfma_f32_16x16x32_bf16(pf[s][1], onesv, L[s], 0, 0, 0);
            #pragma unroll
            for (int dt = 0; dt < 4; ++dt) {
                O[s][dt] = __builtin_amdgcn_mfma_f32_16x16x32_bf16(pf[s][0], vf[dt][0], O[s][dt], 0, 0, 0);
                O[s][dt] = __builtin_amdgcn_mfma_f32_16x16x32_bf16(pf[s][1], vf[dt][1], O[s][dt], 0, 0, 0);
            }
        }
    }

    const int b = bh >> 4, h = bh & 15;
    #pragma unroll
    for (int s = 0; s < 2; ++s) {
        #pragma unroll
        for (int r = 0; r < 4; ++r) {
            const int qi = q0 + wave * 32 + s * 16 + quad * 4 + r;
            if (qi < N_) {
                const float inv = 1.0f / L[s][r];
                unsigned short* op = out + ((size_t)(b * N_ + qi)) * C_ + h * DH_ + l16;
                #pragma unroll
                for (int dt = 0; dt < 4; ++dt) op[dt * 16] = f2h(O[s][dt][r] * inv);
            }
        }
    }
}

// ---------------------------------------------------------------------------
extern "C" void kernel_launch(void* const* d_in, const int* in_sizes, int n_in,
                              void* d_out, int out_size, void* d_ws, size_t ws_size,
                              hipStream_t stream) {
    const float* x      = (const float*)d_in[0];
    const float* sinp   = (const float*)d_in[1];
    const float* cosp   = (const float*)d_in[2];
    const float* w_qkv  = (const float*)d_in[3];
    const float* b_qkv  = (const float*)d_in[4];
    const float* w_proj = (const float*)d_in[5];
    const float* b_proj = (const float*)d_in[6];
    float* out = (float*)d_out;

    unsigned short* p = (unsigned short*)d_ws;
    const size_t xsz  = (size_t)M_ * C_;
    const size_t wqsz = (size_t)3 * C_ * C_;
    const size_t wpsz = (size_t)C_ * C_;
    const size_t hsz  = (size_t)B_ * H_ * N_ * DH_;
    const size_t vtsz = (size_t)B_ * H_ * DH_ * VTS_;
    unsigned short* x_h   = p;            p += xsz;
    unsigned short* wq_t  = p;            p += wqsz;
    unsigned short* wp_t  = p;            p += wpsz;
    unsigned short* q     = p;            p += hsz;
    unsigned short* k     = p;            p += hsz;
    unsigned short* vt    = p;            p += vtsz;
    unsigned short* attnb = p;            p += xsz;

    conv_x_k<<<(int)((xsz / 4 + 255) / 256), 256, 0, stream>>>(x, x_h, (int)(xsz / 4));
    conv_wt_k<<<dim3(3 * C_ / 64, C_ / 64), 256, 0, stream>>>(w_qkv, wq_t, 3 * C_);
    conv_wt_k<<<dim3(C_ / 64, C_ / 64), 256, 0, stream>>>(w_proj, wp_t, C_);

    // QKV projection: single fp16 GEMM, fused RoPE epilogue
    gemm_mfma<1, 128><<<dim3(3 * C_ / 128, (M_ + 127) / 128), 256, 0, stream>>>(
        x_h, wq_t, b_qkv, nullptr, q, k, vt, sinp, cosp, 16);

    attn_k<<<dim3((N_ + 127) / 128, B_ * H_), 256, 0, stream>>>(q, k, vt, attnb);

    // output projection: MT=64 tile -> 688 blocks (2.7/CU)
    gemm_mfma<0, 64><<<dim3(C_ / 128, (M_ + 63) / 64), 256, 0, stream>>>(
        attnb, wp_t, b_proj, out, nullptr, nullptr, nullptr, nullptr, nullptr, 16);
}